// Round 11
// baseline (296.891 us; speedup 1.0000x reference)
//
#include <hip/hip_runtime.h>
#include <hip/hip_bf16.h>

#define KC   1024
#define DD   256
#define NN   32768
#define HWC  1024
#define LOSS_OFF 8388608
#define IDX_OFF  8388609
#define CBT_OFF  2000000   // cbT[256][1024] in out's x_q region; gather overwrites later

// Replicate numpy pairwise_sum of a[i]*a[i], n=256 (validated: absmax 0.0 r2..r10).
__device__ __forceinline__ float np_pairwise_sumsq_256(const float* __restrict__ a) {
#pragma clang fp contract(off)
  float half0, half1;
  {
    const float* p = a;
    float r[8];
#pragma unroll
    for (int j = 0; j < 8; ++j) r[j] = p[j] * p[j];
    for (int i = 8; i < 128; i += 8) {
#pragma unroll
      for (int j = 0; j < 8; ++j) r[j] = r[j] + p[i + j] * p[i + j];
    }
    half0 = ((r[0] + r[1]) + (r[2] + r[3])) + ((r[4] + r[5]) + (r[6] + r[7]));
  }
  {
    const float* p = a + 128;
    float r[8];
#pragma unroll
    for (int j = 0; j < 8; ++j) r[j] = p[j] * p[j];
    for (int i = 8; i < 128; i += 8) {
#pragma unroll
      for (int j = 0; j < 8; ++j) r[j] = r[j] + p[i + j] * p[i + j];
    }
    half1 = ((r[0] + r[1]) + (r[2] + r[3])) + ((r[4] + r[5]) + (r[6] + r[7]));
  }
  return half0 + half1;
}

// K0: e_sq[k] via numpy-pairwise; zero loss accumulator.
__global__ void vq_esq_kernel(const float* __restrict__ cb, float* __restrict__ esq,
                              float* __restrict__ loss_acc) {
  const int k = blockIdx.x * 256 + threadIdx.x;
  if (k == 0) loss_acc[0] = 0.0f;
  if (k < KC) esq[k] = np_pairwise_sumsq_256(cb + ((size_t)k << 8));
}

// K0b: cbT[d][k] = cb[k][d] (1MB, L2-resident; makes argmin e-loads coalesced).
__global__ __launch_bounds__(256) void vq_transpose_kernel(const float* __restrict__ cb,
                                                           float* __restrict__ cbT) {
  const int d = blockIdx.x;     // 0..255
  const int t = threadIdx.x;
#pragma unroll
  for (int q = 0; q < 4; ++q) {
    const int k = (q << 8) + t;
    cbT[(d << 10) + k] = cb[((size_t)k << 8) + d];
  }
}

// K1: fused distance + argmin. 256 threads, 16 rows/block, all 1024 codes.
// Structure as r10 (validated) + SOFTWARE-PIPELINED e-stream: ev double-buffer,
// 2-unrolled chunk loop, LOADE(next) issued before FMACHUNK(curr) — hides the
// ~200-300cyc L2 latency that left real VALU busy at ~39% (r10: VALUBusy 78% on
// the 4-cyc gfx94x formula = 39% at CDNA4's 2-cyc issue).
// LB(256,2): only non-squeezing config on this toolchain (r4/r6/r8 evidence).
__global__ __launch_bounds__(256, 2)
void vq_argmin_kernel(const float* __restrict__ x, const float* __restrict__ cbT,
                      const float* __restrict__ esq, int* __restrict__ idxout,
                      float* __restrict__ out) {
  __shared__ float xs[16][260];    // 16 rows x 256 d (+pad, 16B-aligned rows)
  __shared__ float xsq[16];
  __shared__ float rbest[4][16];
  __shared__ int   rbidx[4][16];

  const int tid  = threadIdx.x;
  const int lane = tid & 63;
  const int w    = tid >> 6;          // 0..3
  const int ws   = w & 1;             // code half
  const int rh   = w >> 1;            // row half
  const int n0   = blockIdx.x << 4;   // 2048 blocks x 16 rows
  const int b    = n0 >> 10;
  const int hw0  = n0 & 1023;
  const float* __restrict__ xb = x + (size_t)b * (DD * HWC) + hw0;

  // Stage x tile: xs[r][d] = x[b, d, hw0+r]; 16-thread groups read 64B lines.
  {
    const int rr = tid & 15;
    const int dq = tid >> 4;
#pragma unroll
    for (int i = 0; i < 16; ++i) {
      const int d = (i << 4) + dq;
      xs[rr][d] = xb[(size_t)d * HWC + rr];
    }
  }
  __syncthreads();

  // x_sq per row, numpy-pairwise bitwise (tie reproduction — do not change).
  if (tid < 16) xsq[tid] = np_pairwise_sumsq_256(&xs[tid][0]);
  __syncthreads();

  const int c0 = (ws << 9) + (lane << 3);          // 8 contiguous codes
  const int r0 = rh << 3;

  float acc[8][8];                                 // [code j][row r]
#pragma unroll
  for (int j = 0; j < 8; ++j)
#pragma unroll
    for (int r = 0; r < 8; ++r) acc[j][r] = 0.0f;

// E[di] = codes c0..c0+3 at dim dbase+di; E[4+di] = codes c0+4..c0+7.
#define LOADE(E, CH)                                                          \
  {                                                                           \
    const int dbase_ = (CH) << 2;                                             \
    _Pragma("unroll")                                                         \
    for (int di = 0; di < 4; ++di) {                                          \
      const float* __restrict__ rp_ = cbT + ((size_t)(dbase_ + di) << 10) + c0; \
      E[di]     = *(const float4*)rp_;                                        \
      E[4 + di] = *(const float4*)(rp_ + 4);                                  \
    }                                                                         \
  }

// Per-acc chain order identical to r10: dims ascending within chunk, chunks
// ascending -> same fl rounding sequence as the validated kernel.
#define FMACHUNK(E, CH)                                                       \
  {                                                                           \
    const int dbase_ = (CH) << 2;                                             \
    _Pragma("unroll")                                                         \
    for (int r = 0; r < 8; ++r) {                                             \
      const float4 xv = *(const float4*)&xs[r0 + r][dbase_];                  \
      acc[0][r] = fmaf(xv.x, E[0].x, acc[0][r]);                              \
      acc[0][r] = fmaf(xv.y, E[1].x, acc[0][r]);                              \
      acc[0][r] = fmaf(xv.z, E[2].x, acc[0][r]);                              \
      acc[0][r] = fmaf(xv.w, E[3].x, acc[0][r]);                              \
      acc[1][r] = fmaf(xv.x, E[0].y, acc[1][r]);                              \
      acc[1][r] = fmaf(xv.y, E[1].y, acc[1][r]);                              \
      acc[1][r] = fmaf(xv.z, E[2].y, acc[1][r]);                              \
      acc[1][r] = fmaf(xv.w, E[3].y, acc[1][r]);                              \
      acc[2][r] = fmaf(xv.x, E[0].z, acc[2][r]);                              \
      acc[2][r] = fmaf(xv.y, E[1].z, acc[2][r]);                              \
      acc[2][r] = fmaf(xv.z, E[2].z, acc[2][r]);                              \
      acc[2][r] = fmaf(xv.w, E[3].z, acc[2][r]);                              \
      acc[3][r] = fmaf(xv.x, E[0].w, acc[3][r]);                              \
      acc[3][r] = fmaf(xv.y, E[1].w, acc[3][r]);                              \
      acc[3][r] = fmaf(xv.z, E[2].w, acc[3][r]);                              \
      acc[3][r] = fmaf(xv.w, E[3].w, acc[3][r]);                              \
      acc[4][r] = fmaf(xv.x, E[4].x, acc[4][r]);                              \
      acc[4][r] = fmaf(xv.y, E[5].x, acc[4][r]);                              \
      acc[4][r] = fmaf(xv.z, E[6].x, acc[4][r]);                              \
      acc[4][r] = fmaf(xv.w, E[7].x, acc[4][r]);                              \
      acc[5][r] = fmaf(xv.x, E[4].y, acc[5][r]);                              \
      acc[5][r] = fmaf(xv.y, E[5].y, acc[5][r]);                              \
      acc[5][r] = fmaf(xv.z, E[6].y, acc[5][r]);                              \
      acc[5][r] = fmaf(xv.w, E[7].y, acc[5][r]);                              \
      acc[6][r] = fmaf(xv.x, E[4].z, acc[6][r]);                              \
      acc[6][r] = fmaf(xv.y, E[5].z, acc[6][r]);                              \
      acc[6][r] = fmaf(xv.z, E[6].z, acc[6][r]);                              \
      acc[6][r] = fmaf(xv.w, E[7].z, acc[6][r]);                              \
      acc[7][r] = fmaf(xv.x, E[4].w, acc[7][r]);                              \
      acc[7][r] = fmaf(xv.y, E[5].w, acc[7][r]);                              \
      acc[7][r] = fmaf(xv.z, E[6].w, acc[7][r]);                              \
      acc[7][r] = fmaf(xv.w, E[7].w, acc[7][r]);                              \
    }                                                                         \
  }

  float4 eb0[8], eb1[8];
  LOADE(eb0, 0)
  for (int ch = 0; ch < 64; ch += 2) {
    LOADE(eb1, ch + 1)        // prefetch ch+1 while FMAs of ch run
    FMACHUNK(eb0, ch)
    if (ch < 62) LOADE(eb0, ch + 2)   // prefetch ch+2 while FMAs of ch+1 run
    FMACHUNK(eb1, ch + 1)
  }
#undef LOADE
#undef FMACHUNK

  // esq for 8 contiguous codes: two float4 loads.
  float eq[8];
  {
    const float4 e0 = *(const float4*)(esq + c0);
    const float4 e1 = *(const float4*)(esq + c0 + 4);
    eq[0]=e0.x; eq[1]=e0.y; eq[2]=e0.z; eq[3]=e0.w;
    eq[4]=e1.x; eq[5]=e1.y; eq[6]=e1.z; eq[7]=e1.w;
  }

#pragma unroll
  for (int r = 0; r < 8; ++r) {
    const float xq = xsq[r0 + r];
    float v; int ki;
    {
      // Reference rounding: fl(e_sq - fl(2*dot)) then fl(t + x_sq). No FMA here.
#pragma clang fp contract(off)
      v = (eq[0] - 2.0f * acc[0][r]) + xq; ki = c0;   // ascending j, strict <
#pragma unroll
      for (int j = 1; j < 8; ++j) {
        const float dj = (eq[j] - 2.0f * acc[j][r]) + xq;
        if (dj < v) { v = dj; ki = c0 + j; }
      }
    }
    // Wave-wide (val,idx) min, lowest k on ties.
#pragma unroll
    for (int off = 32; off >= 1; off >>= 1) {
      const float v2 = __shfl_xor(v, off, 64);
      const int   k2 = __shfl_xor(ki, off, 64);
      if (v2 < v || (v2 == v && k2 < ki)) { v = v2; ki = k2; }
    }
    if (lane == 0) { rbest[w][r0 + r] = v; rbidx[w][r0 + r] = ki; }
  }
  __syncthreads();

  // Merge the two code halves per row (ws=0 then ws=1; strict < keeps lowest k).
  if (tid < 16) {
    const int w0 = (tid >> 3) << 1;    // wave with ws=0 for this row's half
    float bb = rbest[w0][tid];
    int   bi = rbidx[w0][tid];
    const float v1 = rbest[w0 + 1][tid];
    if (v1 < bb) { bb = v1; bi = rbidx[w0 + 1][tid]; }
    idxout[n0 + tid] = bi;
    out[IDX_OFF + n0 + tid] = (float)bi;       // fp32 index output
  }
}

// K2: gather codebook rows per block into LDS, write x_q_st (fp32), accumulate loss.
// Overwrites ALL of out's x_q region (including the cbT scratch area).
__global__ __launch_bounds__(256, 2)
void vq_gather_kernel(const float* __restrict__ x, const float* __restrict__ cb,
                      const int* __restrict__ idxin, float* __restrict__ loss_acc,
                      float* __restrict__ out) {
  __shared__ float qs[64][260];
  __shared__ int   idx_s[64];
  __shared__ float wr[4];

  const int tid  = threadIdx.x;
  const int lane = tid & 63;
  const int w    = tid >> 6;
  const int n0   = blockIdx.x << 6;
  const int b    = n0 >> 10;
  const int hw0  = n0 & 1023;

  if (tid < 64) idx_s[tid] = idxin[n0 + tid];
  __syncthreads();

  const float4* __restrict__ cb4 = (const float4*)cb;
  for (int r = w; r < 64; r += 4) {
    const int c = idx_s[r];
    const float4 v = cb4[((size_t)c << 6) + lane];  // coalesced 1KB row read per wave
    *(float4*)&qs[r][lane << 2] = v;
  }
  __syncthreads();

  float lsum = 0.f;
  const size_t obase = (size_t)b * (DD * HWC) + hw0 + lane;
  for (int i = 0; i < 64; ++i) {
    const int d = (w << 6) + i;
    const size_t o = obase + (size_t)d * HWC;
    const float q  = qs[lane][d];
    const float xv = x[o];
    {
#pragma clang fp contract(off)
      const float df = q - xv;           // fl(x_q - x)
      out[o] = xv + df;                  // x_q_st = fl(x + fl(x_q - x)), fp32
      lsum = fmaf(df, df, lsum);         // loss accumulation (loose threshold)
    }
  }

  for (int off = 32; off > 0; off >>= 1) lsum += __shfl_down(lsum, off, 64);
  if (lane == 0) wr[w] = lsum;
  __syncthreads();
  if (tid == 0) atomicAdd(loss_acc, (wr[0] + wr[1]) + (wr[2] + wr[3]));
}

// K3: loss = 1.5 * mean((x_q - x)^2), fp32
__global__ void vq_loss_kernel(const float* __restrict__ loss_acc,
                               float* __restrict__ out) {
  if (threadIdx.x == 0) {
    const float m = loss_acc[0] / 8388608.0f;
    out[LOSS_OFF] = m + 0.5f * m;
  }
}

extern "C" void kernel_launch(void* const* d_in, const int* in_sizes, int n_in,
                              void* d_out, int out_size, void* d_ws, size_t ws_size,
                              hipStream_t stream) {
  const float* x  = (const float*)d_in[0];   // [32,256,32,32] fp32
  const float* cb = (const float*)d_in[1];   // [1024,256] fp32
  float* out = (float*)d_out;                // [x_q_st | loss | indices] fp32

  float* esq      = (float*)d_ws;            // 1024 floats
  float* loss_acc = esq + 1024;              // 1 float (zeroed by K0 each call)
  int*   idxbuf   = (int*)(esq + 1040);      // 32768 ints
  float* cbT      = out + CBT_OFF;           // 256x1024 floats, overwritten by K2

  hipLaunchKernelGGL(vq_esq_kernel,       dim3(4),    dim3(256), 0, stream, cb, esq, loss_acc);
  hipLaunchKernelGGL(vq_transpose_kernel, dim3(256),  dim3(256), 0, stream, cb, cbT);
  hipLaunchKernelGGL(vq_argmin_kernel,    dim3(2048), dim3(256), 0, stream, x, cbT, esq, idxbuf, out);
  hipLaunchKernelGGL(vq_gather_kernel,    dim3(512),  dim3(256), 0, stream, x, cb, idxbuf, loss_acc, out);
  hipLaunchKernelGGL(vq_loss_kernel,      dim3(1),    dim3(64),  0, stream, loss_acc, out);
}

// Round 12
// 296.811 us; speedup vs baseline: 1.0003x; 1.0003x over previous
//
#include <hip/hip_runtime.h>
#include <hip/hip_bf16.h>

#define KC   1024
#define DD   256
#define NN   32768
#define HWC  1024
#define LOSS_OFF 8388608
#define IDX_OFF  8388609
#define CBT_OFF  2000000   // cbT[256][1024] in out's x_q region; gather overwrites later

// Replicate numpy pairwise_sum of a[i]*a[i], n=256 (validated: absmax 0.0 r2..r11).
__device__ __forceinline__ float np_pairwise_sumsq_256(const float* __restrict__ a) {
#pragma clang fp contract(off)
  float half0, half1;
  {
    const float* p = a;
    float r[8];
#pragma unroll
    for (int j = 0; j < 8; ++j) r[j] = p[j] * p[j];
    for (int i = 8; i < 128; i += 8) {
#pragma unroll
      for (int j = 0; j < 8; ++j) r[j] = r[j] + p[i + j] * p[i + j];
    }
    half0 = ((r[0] + r[1]) + (r[2] + r[3])) + ((r[4] + r[5]) + (r[6] + r[7]));
  }
  {
    const float* p = a + 128;
    float r[8];
#pragma unroll
    for (int j = 0; j < 8; ++j) r[j] = p[j] * p[j];
    for (int i = 8; i < 128; i += 8) {
#pragma unroll
      for (int j = 0; j < 8; ++j) r[j] = r[j] + p[i + j] * p[i + j];
    }
    half1 = ((r[0] + r[1]) + (r[2] + r[3])) + ((r[4] + r[5]) + (r[6] + r[7]));
  }
  return half0 + half1;
}

// K0: e_sq[k] via numpy-pairwise; zero loss accumulator.
__global__ void vq_esq_kernel(const float* __restrict__ cb, float* __restrict__ esq,
                              float* __restrict__ loss_acc) {
  const int k = blockIdx.x * 256 + threadIdx.x;
  if (k == 0) loss_acc[0] = 0.0f;
  if (k < KC) esq[k] = np_pairwise_sumsq_256(cb + ((size_t)k << 8));
}

// K0b: cbT[d][k] = cb[k][d] (1MB, L2-resident; makes argmin e-loads coalesced).
__global__ __launch_bounds__(256) void vq_transpose_kernel(const float* __restrict__ cb,
                                                           float* __restrict__ cbT) {
  const int d = blockIdx.x;     // 0..255
  const int t = threadIdx.x;
#pragma unroll
  for (int q = 0; q < 4; ++q) {
    const int k = (q << 8) + t;
    cbT[(d << 10) + k] = cb[((size_t)k << 8) + d];
  }
}

// K1: fused distance + argmin (r10 structure, validated at 287us).
// 256 threads, 16 rows/block, all 1024 codes; wave w: ws=w&1 code half,
// rh=w>>1 row half; thread: 8 contiguous codes c0 = ws*512 + lane*8.
// Pipe budget per CU: FMA 262Kcyc/SIMD, L1-return 262Kcyc, LDS 197Kcyc;
// at 2 resident blocks (LB(256,2)) these nearly SERIALIZE (689Kcyc observed).
// LB(256,3): 3 blocks/CU = 12 waves -> cross-wave phase overlap of the three
// pipes. VGPR cap at 3 waves/EU = ~170 >> the natural 84 -> no squeeze risk
// (r4/r6/r8 squeezes happened when demand exceeded the tier cap).
__global__ __launch_bounds__(256, 3)
void vq_argmin_kernel(const float* __restrict__ x, const float* __restrict__ cbT,
                      const float* __restrict__ esq, int* __restrict__ idxout,
                      float* __restrict__ out) {
  __shared__ float xs[16][260];    // 16 rows x 256 d (+pad, 16B-aligned rows)
  __shared__ float xsq[16];
  __shared__ float rbest[4][16];
  __shared__ int   rbidx[4][16];

  const int tid  = threadIdx.x;
  const int lane = tid & 63;
  const int w    = tid >> 6;          // 0..3
  const int ws   = w & 1;             // code half
  const int rh   = w >> 1;            // row half
  const int n0   = blockIdx.x << 4;   // 2048 blocks x 16 rows
  const int b    = n0 >> 10;
  const int hw0  = n0 & 1023;
  const float* __restrict__ xb = x + (size_t)b * (DD * HWC) + hw0;

  // Stage x tile: xs[r][d] = x[b, d, hw0+r]; 16-thread groups read 64B lines.
  {
    const int rr = tid & 15;
    const int dq = tid >> 4;
#pragma unroll
    for (int i = 0; i < 16; ++i) {
      const int d = (i << 4) + dq;
      xs[rr][d] = xb[(size_t)d * HWC + rr];
    }
  }
  __syncthreads();

  // x_sq per row, numpy-pairwise bitwise (tie reproduction — do not change).
  if (tid < 16) xsq[tid] = np_pairwise_sumsq_256(&xs[tid][0]);
  __syncthreads();

  const int c0 = (ws << 9) + (lane << 3);          // 8 contiguous codes
  const int r0 = rh << 3;

  float acc[8][8];                                 // [code j][row r]
#pragma unroll
  for (int j = 0; j < 8; ++j)
#pragma unroll
    for (int r = 0; r < 8; ++r) acc[j][r] = 0.0f;

  // 64 chunks x 4 dims. Per chunk: 8 coalesced cbT loads + 8 broadcast
  // ds_read_b128 + 256 FMAs/thread. d ascending per accumulator — identical
  // fl chain order to the validated r10 kernel.
  for (int ch = 0; ch < 64; ++ch) {
    const int dbase = ch << 2;
    float4 eA[4], eB[4];
#pragma unroll
    for (int di = 0; di < 4; ++di) {
      const float* __restrict__ rowp = cbT + ((size_t)(dbase + di) << 10) + c0;
      eA[di] = *(const float4*)rowp;        // codes c0..c0+3 at dim dbase+di
      eB[di] = *(const float4*)(rowp + 4);  // codes c0+4..c0+7
    }
#pragma unroll
    for (int r = 0; r < 8; ++r) {
      const float4 xv = *(const float4*)&xs[r0 + r][dbase];  // uniform -> broadcast
#define VQ_STEP(J, E, C)                                   \
      acc[J][r] = fmaf(xv.x, E[0].C, acc[J][r]);           \
      acc[J][r] = fmaf(xv.y, E[1].C, acc[J][r]);           \
      acc[J][r] = fmaf(xv.z, E[2].C, acc[J][r]);           \
      acc[J][r] = fmaf(xv.w, E[3].C, acc[J][r]);
      VQ_STEP(0, eA, x) VQ_STEP(1, eA, y) VQ_STEP(2, eA, z) VQ_STEP(3, eA, w)
      VQ_STEP(4, eB, x) VQ_STEP(5, eB, y) VQ_STEP(6, eB, z) VQ_STEP(7, eB, w)
#undef VQ_STEP
    }
  }

  // esq for 8 contiguous codes: two float4 loads.
  float eq[8];
  {
    const float4 e0 = *(const float4*)(esq + c0);
    const float4 e1 = *(const float4*)(esq + c0 + 4);
    eq[0]=e0.x; eq[1]=e0.y; eq[2]=e0.z; eq[3]=e0.w;
    eq[4]=e1.x; eq[5]=e1.y; eq[6]=e1.z; eq[7]=e1.w;
  }

#pragma unroll
  for (int r = 0; r < 8; ++r) {
    const float xq = xsq[r0 + r];
    float v; int ki;
    {
      // Reference rounding: fl(e_sq - fl(2*dot)) then fl(t + x_sq). No FMA here.
#pragma clang fp contract(off)
      v = (eq[0] - 2.0f * acc[0][r]) + xq; ki = c0;   // ascending j, strict <
#pragma unroll
      for (int j = 1; j < 8; ++j) {
        const float dj = (eq[j] - 2.0f * acc[j][r]) + xq;
        if (dj < v) { v = dj; ki = c0 + j; }
      }
    }
    // Wave-wide (val,idx) min, lowest k on ties.
#pragma unroll
    for (int off = 32; off >= 1; off >>= 1) {
      const float v2 = __shfl_xor(v, off, 64);
      const int   k2 = __shfl_xor(ki, off, 64);
      if (v2 < v || (v2 == v && k2 < ki)) { v = v2; ki = k2; }
    }
    if (lane == 0) { rbest[w][r0 + r] = v; rbidx[w][r0 + r] = ki; }
  }
  __syncthreads();

  // Merge the two code halves per row (ws=0 then ws=1; strict < keeps lowest k).
  if (tid < 16) {
    const int w0 = (tid >> 3) << 1;    // wave with ws=0 for this row's half
    float bb = rbest[w0][tid];
    int   bi = rbidx[w0][tid];
    const float v1 = rbest[w0 + 1][tid];
    if (v1 < bb) { bb = v1; bi = rbidx[w0 + 1][tid]; }
    idxout[n0 + tid] = bi;
    out[IDX_OFF + n0 + tid] = (float)bi;       // fp32 index output
  }
}

// K2: gather codebook rows per block into LDS, write x_q_st (fp32), accumulate loss.
// Overwrites ALL of out's x_q region (including the cbT scratch area).
__global__ __launch_bounds__(256, 2)
void vq_gather_kernel(const float* __restrict__ x, const float* __restrict__ cb,
                      const int* __restrict__ idxin, float* __restrict__ loss_acc,
                      float* __restrict__ out) {
  __shared__ float qs[64][260];
  __shared__ int   idx_s[64];
  __shared__ float wr[4];

  const int tid  = threadIdx.x;
  const int lane = tid & 63;
  const int w    = tid >> 6;
  const int n0   = blockIdx.x << 6;
  const int b    = n0 >> 10;
  const int hw0  = n0 & 1023;

  if (tid < 64) idx_s[tid] = idxin[n0 + tid];
  __syncthreads();

  const float4* __restrict__ cb4 = (const float4*)cb;
  for (int r = w; r < 64; r += 4) {
    const int c = idx_s[r];
    const float4 v = cb4[((size_t)c << 6) + lane];  // coalesced 1KB row read per wave
    *(float4*)&qs[r][lane << 2] = v;
  }
  __syncthreads();

  float lsum = 0.f;
  const size_t obase = (size_t)b * (DD * HWC) + hw0 + lane;
  for (int i = 0; i < 64; ++i) {
    const int d = (w << 6) + i;
    const size_t o = obase + (size_t)d * HWC;
    const float q  = qs[lane][d];
    const float xv = x[o];
    {
#pragma clang fp contract(off)
      const float df = q - xv;           // fl(x_q - x)
      out[o] = xv + df;                  // x_q_st = fl(x + fl(x_q - x)), fp32
      lsum = fmaf(df, df, lsum);         // loss accumulation (loose threshold)
    }
  }

  for (int off = 32; off > 0; off >>= 1) lsum += __shfl_down(lsum, off, 64);
  if (lane == 0) wr[w] = lsum;
  __syncthreads();
  if (tid == 0) atomicAdd(loss_acc, (wr[0] + wr[1]) + (wr[2] + wr[3]));
}

// K3: loss = 1.5 * mean((x_q - x)^2), fp32
__global__ void vq_loss_kernel(const float* __restrict__ loss_acc,
                               float* __restrict__ out) {
  if (threadIdx.x == 0) {
    const float m = loss_acc[0] / 8388608.0f;
    out[LOSS_OFF] = m + 0.5f * m;
  }
}

extern "C" void kernel_launch(void* const* d_in, const int* in_sizes, int n_in,
                              void* d_out, int out_size, void* d_ws, size_t ws_size,
                              hipStream_t stream) {
  const float* x  = (const float*)d_in[0];   // [32,256,32,32] fp32
  const float* cb = (const float*)d_in[1];   // [1024,256] fp32
  float* out = (float*)d_out;                // [x_q_st | loss | indices] fp32

  float* esq      = (float*)d_ws;            // 1024 floats
  float* loss_acc = esq + 1024;              // 1 float (zeroed by K0 each call)
  int*   idxbuf   = (int*)(esq + 1040);      // 32768 ints
  float* cbT      = out + CBT_OFF;           // 256x1024 floats, overwritten by K2

  hipLaunchKernelGGL(vq_esq_kernel,       dim3(4),    dim3(256), 0, stream, cb, esq, loss_acc);
  hipLaunchKernelGGL(vq_transpose_kernel, dim3(256),  dim3(256), 0, stream, cb, cbT);
  hipLaunchKernelGGL(vq_argmin_kernel,    dim3(2048), dim3(256), 0, stream, x, cbT, esq, idxbuf, out);
  hipLaunchKernelGGL(vq_gather_kernel,    dim3(512),  dim3(256), 0, stream, x, cb, idxbuf, loss_acc, out);
  hipLaunchKernelGGL(vq_loss_kernel,      dim3(1),    dim3(64),  0, stream, loss_acc, out);
}

// Round 13
// 241.373 us; speedup vs baseline: 1.2300x; 1.2297x over previous
//
#include <hip/hip_runtime.h>
#include <hip/hip_bf16.h>

#define KC   1024
#define DD   256
#define NN   32768
#define HWC  1024
#define LOSS_OFF 8388608
#define IDX_OFF  8388609
#define CBT_OFF  2000000   // cbT[256][1024] in out's x_q region; gather overwrites later

// Replicate numpy pairwise_sum of a[i]*a[i], n=256 (validated: absmax 0.0 r2..r12).
__device__ __forceinline__ float np_pairwise_sumsq_256(const float* __restrict__ a) {
#pragma clang fp contract(off)
  float half0, half1;
  {
    const float* p = a;
    float r[8];
#pragma unroll
    for (int j = 0; j < 8; ++j) r[j] = p[j] * p[j];
    for (int i = 8; i < 128; i += 8) {
#pragma unroll
      for (int j = 0; j < 8; ++j) r[j] = r[j] + p[i + j] * p[i + j];
    }
    half0 = ((r[0] + r[1]) + (r[2] + r[3])) + ((r[4] + r[5]) + (r[6] + r[7]));
  }
  {
    const float* p = a + 128;
    float r[8];
#pragma unroll
    for (int j = 0; j < 8; ++j) r[j] = p[j] * p[j];
    for (int i = 8; i < 128; i += 8) {
#pragma unroll
      for (int j = 0; j < 8; ++j) r[j] = r[j] + p[i + j] * p[i + j];
    }
    half1 = ((r[0] + r[1]) + (r[2] + r[3])) + ((r[4] + r[5]) + (r[6] + r[7]));
  }
  return half0 + half1;
}

// K0: e_sq[k] via numpy-pairwise; zero loss accumulator.
__global__ void vq_esq_kernel(const float* __restrict__ cb, float* __restrict__ esq,
                              float* __restrict__ loss_acc) {
  const int k = blockIdx.x * 256 + threadIdx.x;
  if (k == 0) loss_acc[0] = 0.0f;
  if (k < KC) esq[k] = np_pairwise_sumsq_256(cb + ((size_t)k << 8));
}

// K0b: cbT[d][k] = cb[k][d] (1MB, L2-resident; makes argmin e-loads coalesced).
__global__ __launch_bounds__(256) void vq_transpose_kernel(const float* __restrict__ cb,
                                                           float* __restrict__ cbT) {
  const int d = blockIdx.x;     // 0..255
  const int t = threadIdx.x;
#pragma unroll
  for (int q = 0; q < 4; ++q) {
    const int k = (q << 8) + t;
    cbT[(d << 10) + k] = cb[((size_t)k << 8) + d];
  }
}

// K1: fused distance + argmin (r10 work split, validated).
// CHANGE vs r10: x enters the hot loop via wave-uniform SCALAR loads
// (s_load_dwordx8: x[b][d][hw0+r0..+8) is 8 contiguous rows at dim d) into
// SGPRs, double-buffered 1 chunk ahead. Hot loop has ZERO ds_reads -> the LDS
// pipe's ~196Kcyc/CU drops out of the serialized pipe sum (FMA 262K + L1 262K
// + LDS 196K ~= the observed 690Kcyc across r10/r11/r12). FMA operands are
// bit-identical (same memory, same chain order) -> tie machinery untouched.
__global__ __launch_bounds__(256, 2)
void vq_argmin_kernel(const float* __restrict__ x, const float* __restrict__ cbT,
                      const float* __restrict__ esq, int* __restrict__ idxout,
                      float* __restrict__ out) {
  __shared__ float xs[16][260];    // used only for the xsq pairwise computation
  __shared__ float xsq[16];
  __shared__ float rbest[4][16];
  __shared__ int   rbidx[4][16];

  const int tid  = threadIdx.x;
  const int lane = tid & 63;
  const int w    = __builtin_amdgcn_readfirstlane(tid >> 6);  // 0..3, SGPR
  const int ws   = w & 1;             // code half
  const int rh   = w >> 1;            // row half
  const int n0   = blockIdx.x << 4;   // 2048 blocks x 16 rows
  const int b    = n0 >> 10;
  const int hw0  = n0 & 1023;
  const float* __restrict__ xb = x + (size_t)b * (DD * HWC) + hw0;

  // Stage x tile for xsq: xs[r][d] = x[b, d, hw0+r].
  {
    const int rr = tid & 15;
    const int dq = tid >> 4;
#pragma unroll
    for (int i = 0; i < 16; ++i) {
      const int d = (i << 4) + dq;
      xs[rr][d] = xb[(size_t)d * HWC + rr];
    }
  }
  __syncthreads();

  // x_sq per row, numpy-pairwise bitwise (tie reproduction — do not change).
  if (tid < 16) xsq[tid] = np_pairwise_sumsq_256(&xs[tid][0]);
  __syncthreads();

  const int c0 = (ws << 9) + (lane << 3);          // 8 contiguous codes
  const int r0 = rh << 3;                          // uniform (w is SGPR)
  const float* __restrict__ xru = xb + r0;         // wave-uniform base

  float acc[8][8];                                 // [code j][row r]
#pragma unroll
  for (int j = 0; j < 8; ++j)
#pragma unroll
    for (int r = 0; r < 8; ++r) acc[j][r] = 0.0f;

// Wave-uniform x loads for one chunk: XA[di][r] = x[b][dbase+di][hw0+r0+r].
// 8 contiguous floats per dim -> s_load_dwordx8; values live in SGPRs.
#define LOADX(XA, CH)                                                         \
  {                                                                           \
    const int db_ = (CH) << 2;                                                \
    _Pragma("unroll")                                                         \
    for (int di = 0; di < 4; ++di) {                                          \
      const float* __restrict__ rp_ = xru + (size_t)(db_ + di) * HWC;         \
      _Pragma("unroll")                                                       \
      for (int r = 0; r < 8; ++r) XA[di][r] = rp_[r];                         \
    }                                                                         \
  }

// Per-acc chain order identical to r10: dims ascending within chunk, chunks
// ascending. XA[0][r] == old xv.x, XA[1][r] == xv.y, etc. (same memory bits).
#define FMACHUNK(XA, CH)                                                      \
  {                                                                           \
    const int dbase_ = (CH) << 2;                                             \
    float4 eA[4], eB[4];                                                      \
    _Pragma("unroll")                                                         \
    for (int di = 0; di < 4; ++di) {                                          \
      const float* __restrict__ rowp = cbT + ((size_t)(dbase_ + di) << 10) + c0; \
      eA[di] = *(const float4*)rowp;                                          \
      eB[di] = *(const float4*)(rowp + 4);                                    \
    }                                                                         \
    _Pragma("unroll")                                                         \
    for (int r = 0; r < 8; ++r) {                                             \
      acc[0][r] = fmaf(XA[0][r], eA[0].x, acc[0][r]);                         \
      acc[0][r] = fmaf(XA[1][r], eA[1].x, acc[0][r]);                         \
      acc[0][r] = fmaf(XA[2][r], eA[2].x, acc[0][r]);                         \
      acc[0][r] = fmaf(XA[3][r], eA[3].x, acc[0][r]);                         \
      acc[1][r] = fmaf(XA[0][r], eA[0].y, acc[1][r]);                         \
      acc[1][r] = fmaf(XA[1][r], eA[1].y, acc[1][r]);                         \
      acc[1][r] = fmaf(XA[2][r], eA[2].y, acc[1][r]);                         \
      acc[1][r] = fmaf(XA[3][r], eA[3].y, acc[1][r]);                         \
      acc[2][r] = fmaf(XA[0][r], eA[0].z, acc[2][r]);                         \
      acc[2][r] = fmaf(XA[1][r], eA[1].z, acc[2][r]);                         \
      acc[2][r] = fmaf(XA[2][r], eA[2].z, acc[2][r]);                         \
      acc[2][r] = fmaf(XA[3][r], eA[3].z, acc[2][r]);                         \
      acc[3][r] = fmaf(XA[0][r], eA[0].w, acc[3][r]);                         \
      acc[3][r] = fmaf(XA[1][r], eA[1].w, acc[3][r]);                         \
      acc[3][r] = fmaf(XA[2][r], eA[2].w, acc[3][r]);                         \
      acc[3][r] = fmaf(XA[3][r], eA[3].w, acc[3][r]);                         \
      acc[4][r] = fmaf(XA[0][r], eB[0].x, acc[4][r]);                         \
      acc[4][r] = fmaf(XA[1][r], eB[1].x, acc[4][r]);                         \
      acc[4][r] = fmaf(XA[2][r], eB[2].x, acc[4][r]);                         \
      acc[4][r] = fmaf(XA[3][r], eB[3].x, acc[4][r]);                         \
      acc[5][r] = fmaf(XA[0][r], eB[0].y, acc[5][r]);                         \
      acc[5][r] = fmaf(XA[1][r], eB[1].y, acc[5][r]);                         \
      acc[5][r] = fmaf(XA[2][r], eB[2].y, acc[5][r]);                         \
      acc[5][r] = fmaf(XA[3][r], eB[3].y, acc[5][r]);                         \
      acc[6][r] = fmaf(XA[0][r], eB[0].z, acc[6][r]);                         \
      acc[6][r] = fmaf(XA[1][r], eB[1].z, acc[6][r]);                         \
      acc[6][r] = fmaf(XA[2][r], eB[2].z, acc[6][r]);                         \
      acc[6][r] = fmaf(XA[3][r], eB[3].z, acc[6][r]);                         \
      acc[7][r] = fmaf(XA[0][r], eB[0].w, acc[7][r]);                         \
      acc[7][r] = fmaf(XA[1][r], eB[1].w, acc[7][r]);                         \
      acc[7][r] = fmaf(XA[2][r], eB[2].w, acc[7][r]);                         \
      acc[7][r] = fmaf(XA[3][r], eB[3].w, acc[7][r]);                         \
    }                                                                         \
  }

  float xa0[4][8], xa1[4][8];
  LOADX(xa0, 0)
  for (int ch = 0; ch < 64; ch += 2) {
    LOADX(xa1, ch + 1)                 // scalar prefetch: hides K$/L2 latency
    FMACHUNK(xa0, ch)
    if (ch < 62) LOADX(xa0, ch + 2)
    FMACHUNK(xa1, ch + 1)
  }
#undef LOADX
#undef FMACHUNK

  // esq for 8 contiguous codes: two float4 loads.
  float eq[8];
  {
    const float4 e0 = *(const float4*)(esq + c0);
    const float4 e1 = *(const float4*)(esq + c0 + 4);
    eq[0]=e0.x; eq[1]=e0.y; eq[2]=e0.z; eq[3]=e0.w;
    eq[4]=e1.x; eq[5]=e1.y; eq[6]=e1.z; eq[7]=e1.w;
  }

#pragma unroll
  for (int r = 0; r < 8; ++r) {
    const float xq = xsq[r0 + r];
    float v; int ki;
    {
      // Reference rounding: fl(e_sq - fl(2*dot)) then fl(t + x_sq). No FMA here.
#pragma clang fp contract(off)
      v = (eq[0] - 2.0f * acc[0][r]) + xq; ki = c0;   // ascending j, strict <
#pragma unroll
      for (int j = 1; j < 8; ++j) {
        const float dj = (eq[j] - 2.0f * acc[j][r]) + xq;
        if (dj < v) { v = dj; ki = c0 + j; }
      }
    }
    // Wave-wide (val,idx) min, lowest k on ties.
#pragma unroll
    for (int off = 32; off >= 1; off >>= 1) {
      const float v2 = __shfl_xor(v, off, 64);
      const int   k2 = __shfl_xor(ki, off, 64);
      if (v2 < v || (v2 == v && k2 < ki)) { v = v2; ki = k2; }
    }
    if (lane == 0) { rbest[w][r0 + r] = v; rbidx[w][r0 + r] = ki; }
  }
  __syncthreads();

  // Merge the two code halves per row (ws=0 then ws=1; strict < keeps lowest k).
  if (tid < 16) {
    const int w0 = (tid >> 3) << 1;    // wave with ws=0 for this row's half
    float bb = rbest[w0][tid];
    int   bi = rbidx[w0][tid];
    const float v1 = rbest[w0 + 1][tid];
    if (v1 < bb) { bb = v1; bi = rbidx[w0 + 1][tid]; }
    idxout[n0 + tid] = bi;
    out[IDX_OFF + n0 + tid] = (float)bi;       // fp32 index output
  }
}

// K2: gather codebook rows per block into LDS, write x_q_st (fp32), accumulate loss.
// Overwrites ALL of out's x_q region (including the cbT scratch area).
__global__ __launch_bounds__(256, 2)
void vq_gather_kernel(const float* __restrict__ x, const float* __restrict__ cb,
                      const int* __restrict__ idxin, float* __restrict__ loss_acc,
                      float* __restrict__ out) {
  __shared__ float qs[64][260];
  __shared__ int   idx_s[64];
  __shared__ float wr[4];

  const int tid  = threadIdx.x;
  const int lane = tid & 63;
  const int w    = tid >> 6;
  const int n0   = blockIdx.x << 6;
  const int b    = n0 >> 10;
  const int hw0  = n0 & 1023;

  if (tid < 64) idx_s[tid] = idxin[n0 + tid];
  __syncthreads();

  const float4* __restrict__ cb4 = (const float4*)cb;
  for (int r = w; r < 64; r += 4) {
    const int c = idx_s[r];
    const float4 v = cb4[((size_t)c << 6) + lane];  // coalesced 1KB row read per wave
    *(float4*)&qs[r][lane << 2] = v;
  }
  __syncthreads();

  float lsum = 0.f;
  const size_t obase = (size_t)b * (DD * HWC) + hw0 + lane;
  for (int i = 0; i < 64; ++i) {
    const int d = (w << 6) + i;
    const size_t o = obase + (size_t)d * HWC;
    const float q  = qs[lane][d];
    const float xv = x[o];
    {
#pragma clang fp contract(off)
      const float df = q - xv;           // fl(x_q - x)
      out[o] = xv + df;                  // x_q_st = fl(x + fl(x_q - x)), fp32
      lsum = fmaf(df, df, lsum);         // loss accumulation (loose threshold)
    }
  }

  for (int off = 32; off > 0; off >>= 1) lsum += __shfl_down(lsum, off, 64);
  if (lane == 0) wr[w] = lsum;
  __syncthreads();
  if (tid == 0) atomicAdd(loss_acc, (wr[0] + wr[1]) + (wr[2] + wr[3]));
}

// K3: loss = 1.5 * mean((x_q - x)^2), fp32
__global__ void vq_loss_kernel(const float* __restrict__ loss_acc,
                               float* __restrict__ out) {
  if (threadIdx.x == 0) {
    const float m = loss_acc[0] / 8388608.0f;
    out[LOSS_OFF] = m + 0.5f * m;
  }
}

extern "C" void kernel_launch(void* const* d_in, const int* in_sizes, int n_in,
                              void* d_out, int out_size, void* d_ws, size_t ws_size,
                              hipStream_t stream) {
  const float* x  = (const float*)d_in[0];   // [32,256,32,32] fp32
  const float* cb = (const float*)d_in[1];   // [1024,256] fp32
  float* out = (float*)d_out;                // [x_q_st | loss | indices] fp32

  float* esq      = (float*)d_ws;            // 1024 floats
  float* loss_acc = esq + 1024;              // 1 float (zeroed by K0 each call)
  int*   idxbuf   = (int*)(esq + 1040);      // 32768 ints
  float* cbT      = out + CBT_OFF;           // 256x1024 floats, overwritten by K2

  hipLaunchKernelGGL(vq_esq_kernel,       dim3(4),    dim3(256), 0, stream, cb, esq, loss_acc);
  hipLaunchKernelGGL(vq_transpose_kernel, dim3(256),  dim3(256), 0, stream, cb, cbT);
  hipLaunchKernelGGL(vq_argmin_kernel,    dim3(2048), dim3(256), 0, stream, x, cbT, esq, idxbuf, out);
  hipLaunchKernelGGL(vq_gather_kernel,    dim3(512),  dim3(256), 0, stream, x, cb, idxbuf, loss_acc, out);
  hipLaunchKernelGGL(vq_loss_kernel,      dim3(1),    dim3(64),  0, stream, loss_acc, out);
}